// Round 6
// baseline (10168.286 us; speedup 1.0000x reference)
//
#include <hip/hip_runtime.h>

// MatchLSTM, fp32, round 6.
// vs R5: (1) match A-phase merged into BC (each BC block computes q for its
// own row via k-major WmT) -> 2 hops/step instead of 3; (2) BC role mapped to
// (cg=bb&7, bg=bb>>3) so each bg-group's BC->D chain is block-disjoint from
// other groups (independent pipeline progress); (3) premise+hypothesis
// encoders run CONCURRENTLY in one kernel (blocks 0-127 / 128-255, 16 rows
// per block, all 4 gates per thread -> no gate-exchange LDS hop).

#define NWG 256
#define TPB 512

typedef float f8v __attribute__((ext_vector_type(8)));

// ---- workspace layout (float offsets) ----
#define O_XPP      0ull          // [64][128][2048] premise input proj (+bias)
#define O_HTMW     0ull          // overlay after encoders: [32][128][2048]
#define O_HTWT     8388608ull    // [32][128][512]
#define O_WSHS     10485760ull   // [64][128][512]
#define O_XPH      16777216ull   // [32][128][2048]
#define O_HST      25165824ull   // [64][512][128]  masked premise h (k-major)
#define O_HS2      29360128ull   // [64][128][512]  masked premise h (h-major)
#define O_HTT      33554432ull   // [32][512][128]  masked hyp h (k-major)
#define O_WIHTP    35651584ull   // [300][2048] perm
#define O_WIHTH    36265984ull
#define O_WHHPP    36880384ull   // [512 hc][4 gate][512 k] premise Whh
#define O_WHHPH    37928960ull   // [512 hc][4 gate][512 k] hyp Whh
#define O_DW       38977536ull   // [1024 pair-rows][1024 k][2] match (mWihL | mWhh)
#define O_WST      41074688ull   // [512][512] k-major
#define O_WTT      41336832ull
#define O_MWIHRT   41598976ull   // [512][2048] perm
#define O_BPP      42647552ull   // [2048] perm biases
#define O_BPH      42649600ull
#define O_BPM      42651648ull
#define O_HT2      42653696ull   // [2][128][512] premise h double buffer (coherent)
#define O_HMT2     42784768ull   // [2][128][512] hyp-enc h dbuf, then match h dbuf
#define O_AK2      42981376ull   // [128][512] (coherent)
#define O_HLAST    43046912ull   // [128][512] (coherent)
#define O_WMT      43112448ull   // [512 k][512 c] Wm transposed
#define WS_FLOATS  43374592ull

__device__ unsigned g_FE[NWG * 16];      // encoder step flags (64B padded)
__device__ unsigned g_FB[NWG * 16];      // match BC flags
__device__ unsigned g_FD[NWG * 16];      // match D flags

struct Params {
  const int* premise; const int* plen; const int* hyp; const int* hlen;
  const float* embed;
  const float* pWih; const float* pWhh; const float* pb;
  const float* hWih; const float* hWhh; const float* hb;
  const float* mWih; const float* mWhh; const float* mb;
  const float* we; const float* Ws; const float* Wt; const float* Wm;
  const float* fcW; const float* fcb;
  float* out; float* ws;
};

// ---- coherent (system-scope, L2-bypassing) accessors for mutable state ----
__device__ __forceinline__ float2 sysld2(const float* p){
  unsigned long long u = __hip_atomic_load((const unsigned long long*)p,
      __ATOMIC_RELAXED, __HIP_MEMORY_SCOPE_SYSTEM);
  union { unsigned long long u; float2 f; } c; c.u = u; return c.f;
}
__device__ __forceinline__ void sysst(float* p, float v){
  union { float f; unsigned u; } c; c.f = v;
  __hip_atomic_store((unsigned*)p, c.u, __ATOMIC_RELAXED, __HIP_MEMORY_SCOPE_SYSTEM);
}
__device__ __forceinline__ void fbump(unsigned* a, unsigned v){
  __hip_atomic_store(a, v, __ATOMIC_RELAXED, __HIP_MEMORY_SCOPE_SYSTEM);
}
__device__ __forceinline__ unsigned fread_(const unsigned* a){
  return __hip_atomic_load(a, __ATOMIC_RELAXED, __HIP_MEMORY_SCOPE_SYSTEM);
}
__device__ __forceinline__ void waitflag(const unsigned* a, unsigned tgt){
  while ((int)(fread_(a) - tgt) < 0) __builtin_amdgcn_s_sleep(2);
}

__device__ __forceinline__ float sigf(float x){ return 1.0f/(1.0f + __expf(-x)); }
__device__ __forceinline__ float tanhf_(float x){ return 2.0f/(1.0f + __expf(-2.0f*x)) - 1.0f; }

__device__ __forceinline__ float wsum(float v){
  #pragma unroll
  for (int o = 32; o > 0; o >>= 1) v += __shfl_xor(v, o, 64);
  return v;
}
__device__ __forceinline__ float wmaxr(float v){
  #pragma unroll
  for (int o = 32; o > 0; o >>= 1) v = fmaxf(v, __shfl_xor(v, o, 64));
  return v;
}

// ================= S0: weight layout transforms (grid 1024) =================
__global__ __launch_bounds__(TPB) void k_s0(Params p){
  const int tid0 = blockIdx.x * TPB + threadIdx.x;
  const int stride = gridDim.x * TPB;
  float* const ws = p.ws;
  float* const WihTp  = ws + O_WIHTP;
  float* const WihTh  = ws + O_WIHTH;
  float* const WhhPP  = ws + O_WHHPP;
  float* const WhhPH  = ws + O_WHHPH;
  float* const DW     = ws + O_DW;
  float* const WsT    = ws + O_WST;
  float* const WtT    = ws + O_WTT;
  float* const WmT    = ws + O_WMT;
  float* const mWihRT = ws + O_MWIHRT;
  float* const bpP    = ws + O_BPP;
  float* const bpH    = ws + O_BPH;
  float* const bpM    = ws + O_BPM;

  for (int idx = tid0; idx < 300*2048; idx += stride){
    int e = idx >> 11, jp = idx & 2047;
    int oc = (jp & 3) * 512 + (jp >> 2);
    WihTp[idx] = p.pWih[(size_t)oc*300 + e];
    WihTh[idx] = p.hWih[(size_t)oc*300 + e];
  }
  // encoder recurrent weights: [hc][gate][k]
  for (int idx = tid0; idx < 512*4*512; idx += stride){
    int k = idx & 511, g = (idx >> 9) & 3, hc = idx >> 11;
    int oc = g*512 + hc;
    WhhPP[idx] = p.pWhh[(size_t)oc*512 + k];
    WhhPH[idx] = p.hWhh[(size_t)oc*512 + k];
  }
  for (int idx = tid0; idx < 1024*1024*2; idx += stride){
    int g = idx & 1, k = (idx >> 1) & 1023, pp = idx >> 11;
    int hc = pp >> 1, gp = pp & 1, oc = (gp*2+g)*512 + hc;
    DW[idx] = (k < 512) ? p.mWih[(size_t)oc*1024 + k]
                        : p.mWhh[(size_t)oc*512 + (k - 512)];
  }
  for (int idx = tid0; idx < 512*512; idx += stride){
    int k = idx >> 9, h = idx & 511;
    WsT[idx] = p.Ws[(size_t)h*512 + k];
    WtT[idx] = p.Wt[(size_t)h*512 + k];
    WmT[idx] = p.Wm[(size_t)h*512 + k];   // [k][c]
  }
  for (int idx = tid0; idx < 512*2048; idx += stride){
    int k = idx >> 11, jp = idx & 2047;
    int oc = (jp & 3) * 512 + (jp >> 2);
    mWihRT[idx] = p.mWih[(size_t)oc*1024 + 512 + k];
  }
  for (int idx = tid0; idx < 2048; idx += stride){
    int oc = (idx & 3) * 512 + (idx >> 2);
    bpP[idx] = p.pb[oc]; bpH[idx] = p.hb[oc]; bpM[idx] = p.mb[oc];
  }
}

// ================= S1: XP = embed[tokens] @ WihT + bias (grid 768) ==========
__global__ __launch_bounds__(TPB) void k_s1(Params p){
  const int tid = threadIdx.x, lane = tid & 63, wave = tid >> 6;
  const int gwave = blockIdx.x * 8 + wave;
  const int wstride = gridDim.x * 8;
  float* const ws = p.ws;
  float* const XPp   = ws + O_XPP;
  float* const XPh   = ws + O_XPH;
  const float* WihTp = ws + O_WIHTP;
  const float* WihTh = ws + O_WIHTH;
  const float* bpP   = ws + O_BPP;
  const float* bpH   = ws + O_BPH;

  for (int task = gwave; task < 6144; task += wstride){
    const bool prem = task < 4096;
    int rb, cb;
    if (prem){ cb = task >> 10; rb = task & 1023; }
    else { int t2 = task - 4096; cb = t2 >> 9; rb = t2 & 511; }
    const int r0 = rb * 8;
    const int* toks = prem ? p.premise : p.hyp;
    const float* wT = prem ? WihTp : WihTh;
    const float* bias = prem ? bpP : bpH;
    float* outp = prem ? XPp : XPh;
    const int j0 = cb * 512 + lane * 8;
    const float* xr[8];
    #pragma unroll
    for (int r = 0; r < 8; ++r) xr[r] = p.embed + (size_t)toks[r0 + r] * 300;
    f8v bias8 = *(const f8v*)(bias + j0);
    float acc[8][8];
    #pragma unroll
    for (int r = 0; r < 8; ++r){
      #pragma unroll
      for (int i = 0; i < 8; ++i) acc[r][i] = 0.f;
    }
    for (int e = 0; e < 300; ++e){
      f8v w8 = *(const f8v*)(wT + (size_t)e * 2048 + j0);
      #pragma unroll
      for (int r = 0; r < 8; ++r){
        float xv = xr[r][e];
        #pragma unroll
        for (int i = 0; i < 8; ++i) acc[r][i] += xv * w8[i];
      }
    }
    #pragma unroll
    for (int r = 0; r < 8; ++r){
      f8v o8;
      #pragma unroll
      for (int i = 0; i < 8; ++i) o8[i] = acc[r][i] + bias8[i];
      *(f8v*)(outp + (size_t)(r0 + r) * 2048 + j0) = o8;
    }
  }
}

// ====== fused encoders: blocks 0-127 premise, 128-255 hypothesis ============
// Block = (cg: 32 h-cols, bg: 16 batch rows). Thread (b16,hc32) owns ALL 4
// gates of (b,hc); c-state in a register; no gate exchange needed.
__global__ __launch_bounds__(TPB, 2) void k_enc(Params p){
  const int wg = blockIdx.x, tid = threadIdx.x;
  const bool prem = wg < 128;
  const int lw = prem ? wg : wg - 128;
  const int cg = lw & 15, bg = lw >> 4;            // bg 0..7
  const int T = prem ? 64 : 32;
  const float* XP  = p.ws + (prem ? O_XPP : O_XPH);
  const float* Wg  = p.ws + (prem ? O_WHHPP : O_WHHPH);
  const int* lens  = prem ? p.plen : p.hlen;
  float* hbuf      = p.ws + (prem ? O_HT2 : O_HMT2);
  float* houtT     = p.ws + (prem ? O_HST : O_HTT);
  float* hout2     = prem ? (p.ws + O_HS2) : nullptr;
  __shared__ float stage[16*520];                  // bank-balanced staging
  __shared__ unsigned shB;
  if (tid == 0) shB = fread_(&g_FE[wg*16]);
  __syncthreads();
  const unsigned B = shB;
  const int b16 = tid >> 5, hc32 = tid & 31;
  const int b = bg*16 + b16, hc = cg*32 + hc32;
  const float* wrow = Wg + (size_t)hc * 2048;      // [4][512]
  const int mylen = lens[b];
  const int srow = tid & 15, schunk = (tid >> 4) & 31;
  const int flagbase = (prem ? 0 : 128) + bg*16;
  float c_reg = 0.f;

  for (int t = 0; t < T; ++t){
    const float* hin = hbuf + (size_t)(t & 1) * 65536;
    float*       hout = hbuf + (size_t)((t + 1) & 1) * 65536;
    if (t > 0){
      if (tid < 16) waitflag(&g_FE[(unsigned)(flagbase + tid)*16], B + t);
      __syncthreads();
      const float* src = hin + (size_t)(bg*16 + srow)*512 + schunk*16;
      float* dst = stage + srow*520 + schunk*16;
      #pragma unroll
      for (int i = 0; i < 16; i += 4){
        float2 va = sysld2(src + i), vb = sysld2(src + i + 2);
        float4 w = {va.x, va.y, vb.x, vb.y};
        *(float4*)(dst + i) = w;
      }
    }
    __syncthreads();
    float4 xg = *(const float4*)(XP + ((size_t)t*128 + b)*2048 + hc*4);
    float a0 = xg.x, a1 = xg.y, a2 = xg.z, a3 = xg.w;
    if (t > 0){
      const float* hr = stage + b16*520;
      #pragma unroll 2
      for (int k = 0; k < 512; k += 4){
        float4 h4 = *(const float4*)(hr + k);
        float4 w0 = *(const float4*)(wrow + k);
        float4 w1 = *(const float4*)(wrow + 512 + k);
        float4 w2 = *(const float4*)(wrow + 1024 + k);
        float4 w3 = *(const float4*)(wrow + 1536 + k);
        a0 += h4.x*w0.x + h4.y*w0.y + h4.z*w0.z + h4.w*w0.w;
        a1 += h4.x*w1.x + h4.y*w1.y + h4.z*w1.z + h4.w*w1.w;
        a2 += h4.x*w2.x + h4.y*w2.y + h4.z*w2.z + h4.w*w2.w;
        a3 += h4.x*w3.x + h4.y*w3.y + h4.z*w3.z + h4.w*w3.w;
      }
    }
    float iv = sigf(a0), fv = sigf(a1), gv = tanhf_(a2), ov = sigf(a3);
    c_reg = fv * c_reg + iv * gv;
    float hv = ov * tanhf_(c_reg);
    sysst(hout + (size_t)b*512 + hc, hv);
    float hm = (t < mylen) ? hv : 0.f;
    houtT[((size_t)t*512 + hc)*128 + b] = hm;
    if (hout2) hout2[((size_t)t*128 + b)*512 + hc] = hm;
    __syncthreads();
    if (tid == 0) fbump(&g_FE[wg*16], B + t + 1);
  }
}

// ================= S4: Ws_hs, htWt, htmW (grid 448) =========================
__global__ __launch_bounds__(TPB) void k_s4(Params p){
  const int tid = threadIdx.x, lane = tid & 63, wave = tid >> 6;
  const int gwave = blockIdx.x * 8 + wave;
  const int wstride = gridDim.x * 8;
  float* const ws = p.ws;
  const float* h_sT   = ws + O_HST;
  const float* h_tT   = ws + O_HTT;
  const float* WsT    = ws + O_WST;
  const float* WtT    = ws + O_WTT;
  const float* mWihRT = ws + O_MWIHRT;
  const float* bpM    = ws + O_BPM;
  float* const Ws_hs  = ws + O_WSHS;
  float* const htWt   = ws + O_HTWT;
  float* const htmW   = ws + O_HTMW;

  for (int task = gwave; task < 3584; task += wstride){
    const float* src; const float* wT; const float* bias; float* outp;
    int rb, cb, cols;
    if (task < 1024){ rb = task;        cb = 0;            src = h_sT; wT = WsT;    bias = nullptr; outp = Ws_hs; cols = 512; }
    else if (task < 1536){ rb = task-1024; cb = 0;         src = h_tT; wT = WtT;    bias = nullptr; outp = htWt;  cols = 512; }
    else { int t2 = task - 1536; cb = t2 >> 9; rb = t2 & 511; src = h_tT; wT = mWihRT; bias = bpM;  outp = htmW;  cols = 2048; }
    const int r0 = rb * 8;
    const int j0 = cb * 512 + lane * 8;
    const float* xr[8];
    #pragma unroll
    for (int r = 0; r < 8; ++r){
      int row = r0 + r;
      xr[r] = src + (size_t)(row >> 7) * 65536 + (row & 127);  // [t][k][b]
    }
    f8v bias8 = {0,0,0,0,0,0,0,0};
    if (bias) bias8 = *(const f8v*)(bias + j0);
    float acc[8][8];
    #pragma unroll
    for (int r = 0; r < 8; ++r){
      #pragma unroll
      for (int i = 0; i < 8; ++i) acc[r][i] = 0.f;
    }
    for (int k = 0; k < 512; ++k){
      f8v w8 = *(const f8v*)(wT + (size_t)k * cols + j0);
      #pragma unroll
      for (int r = 0; r < 8; ++r){
        float xv = xr[r][(size_t)k * 128];
        #pragma unroll
        for (int i = 0; i < 8; ++i) acc[r][i] += xv * w8[i];
      }
    }
    #pragma unroll
    for (int r = 0; r < 8; ++r){
      f8v o8;
      #pragma unroll
      for (int i = 0; i < 8; ++i) o8[i] = acc[r][i] + bias8[i];
      *(f8v*)(outp + (size_t)(r0 + r) * (size_t)cols + j0) = o8;
    }
  }
}

// ================= match-LSTM loop + fc (persistent, grid 256) ==============
// 2 phases/step. BC role: block (cg<8, bg) owns row bb=bg*8+cg -> q, scores,
// softmax, a_k. D role (all blocks): gates for (32 cols x 8 rows of bg).
__global__ __launch_bounds__(TPB, 2) void k_match(Params p){
  const int wg = blockIdx.x, tid = threadIdx.x;
  const int lane = tid & 63, wave = tid >> 6;
  const int cg = wg & 15, bg = wg >> 4;
  const bool bcrole = cg < 8;
  const int bb = bg*8 + cg;                 // valid if bcrole
  __shared__ float lds[8736];               // BC: hm[512]|q[512]|sc[64]|al[64]
  __shared__ unsigned shB;                  // D : stage2[8][1028] + xch2[512]
  if (tid == 0) shB = fread_(&g_FD[wg*16]);
  __syncthreads();
  const unsigned B = shB;

  float* const ws = p.ws;
  const float* htmW  = ws + O_HTMW;
  const float* htWt  = ws + O_HTWT;
  const float* Ws_hs = ws + O_WSHS;
  const float* h_s2  = ws + O_HS2;
  const float* DW    = ws + O_DW;
  const float* WmT   = ws + O_WMT;
  float* const hmT2  = ws + O_HMT2;
  float* const ak2   = ws + O_AK2;
  float* const hlast = ws + O_HLAST;

  const int b8 = tid & 7, hc32d = (tid >> 3) & 31, gp = tid >> 8;
  const int mb_ = bg*8 + b8, mhc = cg*32 + hc32d;
  const float* dwrow = DW + (size_t)(mhc*2 + gp) * 2048;   // [1024][2]
  const int hyplen_b = p.hlen[mb_];
  float* stage2 = lds;
  float* xch2   = lds + 8*1028;
  float cm_reg = 0.f, hl_reg = 0.f;

  for (int k = 0; k < 32; ++k){
    const float* hmin  = hmT2 + (size_t)(k & 1) * 65536;
    float*       hmout = hmT2 + (size_t)((k + 1) & 1) * 65536;

    // ---- BC phase (blocks with cg<8): q + scores + softmax + a_k ----
    if (bcrole){
      if (k > 0){
        // RAW h_m(k) from the 16 D-blocks of this bg; also covers WAR on ak2.
        if (tid < 16) waitflag(&g_FD[(unsigned)(bg*16 + tid)*16], B + k);
        __syncthreads();
        if (tid < 256){
          float2 v = sysld2(hmin + (size_t)bb*512 + tid*2);
          lds[tid*2] = v.x; lds[tid*2+1] = v.y;           // hmL
        }
      }
      __syncthreads();
      float qv = htWt[((size_t)k*128 + bb)*512 + tid];
      if (k > 0){
        float q0 = 0.f, q1 = 0.f, q2 = 0.f, q3 = 0.f;
        for (int kk = 0; kk < 512; kk += 4){
          q0 += lds[kk]   * WmT[(size_t)(kk)  *512 + tid];
          q1 += lds[kk+1] * WmT[(size_t)(kk+1)*512 + tid];
          q2 += lds[kk+2] * WmT[(size_t)(kk+2)*512 + tid];
          q3 += lds[kk+3] * WmT[(size_t)(kk+3)*512 + tid];
        }
        qv += (q0 + q1) + (q2 + q3);
      }
      __syncthreads();
      lds[512 + tid] = qv;                                // qL
      __syncthreads();
      float q8[8];
      #pragma unroll
      for (int j = 0; j < 8; ++j) q8[j] = lds[512 + lane*8 + j];
      float4 e0 = *(const float4*)(p.we + lane*8);
      float4 e1 = *(const float4*)(p.we + lane*8 + 4);
      #pragma unroll
      for (int si = 0; si < 8; ++si){
        int s = wave*8 + si;
        const float* wsr = Ws_hs + ((size_t)s*128 + bb)*512 + lane*8;
        float4 s0 = *(const float4*)wsr;
        float4 s1 = *(const float4*)(wsr + 4);
        float v = tanhf_(s0.x + q8[0])*e0.x + tanhf_(s0.y + q8[1])*e0.y
                + tanhf_(s0.z + q8[2])*e0.z + tanhf_(s0.w + q8[3])*e0.w
                + tanhf_(s1.x + q8[4])*e1.x + tanhf_(s1.y + q8[5])*e1.y
                + tanhf_(s1.z + q8[6])*e1.z + tanhf_(s1.w + q8[7])*e1.w;
        v = wsum(v);
        if (lane == 0) lds[1024 + s] = v;
      }
      __syncthreads();
      if (wave == 0){
        float v = lds[1024 + lane];
        float m = wmaxr(v);
        float ex = __expf(v - m);
        float sm = wsum(ex);
        lds[1088 + lane] = ex / sm;
      }
      __syncthreads();
      {
        float acc = 0.f;
        const float* hsb = h_s2 + (size_t)bb*512 + tid;
        #pragma unroll 4
        for (int s = 0; s < 64; s += 4){
          float4 al = *(const float4*)(lds + 1088 + s);
          acc += al.x * hsb[(size_t)(s+0)*65536]
               + al.y * hsb[(size_t)(s+1)*65536]
               + al.z * hsb[(size_t)(s+2)*65536]
               + al.w * hsb[(size_t)(s+3)*65536];
        }
        sysst(ak2 + (size_t)bb*512 + tid, acc);
      }
      __syncthreads();
      if (tid == 0) fbump(&g_FB[wg*16], B + k + 1);
    }

    // ---- D phase (all blocks): gates = htmW[k] + [a_k|h_m] @ DW ----
    if (!bcrole && k > 0){
      if (tid < 16) waitflag(&g_FD[(unsigned)(bg*16 + tid)*16], B + k);
    }
    if (tid >= 16 && tid < 24)
      waitflag(&g_FB[(unsigned)(bg*16 + (tid - 16))*16], B + k + 1);
    __syncthreads();
    { // stage [a_k | h_m] (8 rows x 1024); h_m half zero at k==0
      const int sb2 = tid >> 6, c0 = (tid & 63) * 16;
      float* dst = stage2 + sb2*1028 + c0;
      if (c0 < 512){
        const float* src = ak2 + (size_t)(bg*8 + sb2)*512 + c0;
        #pragma unroll
        for (int i = 0; i < 16; i += 4){
          float2 va = sysld2(src + i), vb = sysld2(src + i + 2);
          float4 w = {va.x, va.y, vb.x, vb.y};
          *(float4*)(dst + i) = w;
        }
      } else if (k > 0){
        const float* src = hmin + (size_t)(bg*8 + sb2)*512 + (c0 - 512);
        #pragma unroll
        for (int i = 0; i < 16; i += 4){
          float2 va = sysld2(src + i), vb = sysld2(src + i + 2);
          float4 w = {va.x, va.y, vb.x, vb.y};
          *(float4*)(dst + i) = w;
        }
      } else {
        float4 z = {0.f, 0.f, 0.f, 0.f};
        #pragma unroll
        for (int i = 0; i < 16; i += 4) *(float4*)(dst + i) = z;
      }
    }
    __syncthreads();
    {
      float a0 = 0.f, a1 = 0.f;
      const float* hr = stage2 + b8*1028;
      #pragma unroll 2
      for (int kk = 0; kk < 1024; kk += 4){
        float4 h4 = *(const float4*)(hr + kk);
        float4 wA = *(const float4*)(dwrow + kk*2);
        float4 wB = *(const float4*)(dwrow + kk*2 + 4);
        a0 += h4.x*wA.x + h4.y*wA.z + h4.z*wB.x + h4.w*wB.z;
        a1 += h4.x*wA.y + h4.y*wA.w + h4.z*wB.y + h4.w*wB.w;
      }
      float2 xg = *(const float2*)(htmW + ((size_t)k*128 + mb_)*2048 + mhc*4 + gp*2);
      a0 += xg.x; a1 += xg.y;
      if (gp == 1){ xch2[(b8*32+hc32d)*2+0] = a0; xch2[(b8*32+hc32d)*2+1] = a1; }
      __syncthreads();
      if (gp == 0){
        float gg = xch2[(b8*32+hc32d)*2+0], go = xch2[(b8*32+hc32d)*2+1];
        float iv = sigf(a0), fv = sigf(a1), gv = tanhf_(gg), ov = sigf(go);
        cm_reg = fv * cm_reg + iv * gv;
        float hv = ov * tanhf_(cm_reg);
        sysst(hmout + (size_t)mb_*512 + mhc, hv);
        if (k + 1 == hyplen_b) hl_reg = hv;
      }
    }
    __syncthreads();
    if (tid == 0) fbump(&g_FD[wg*16], B + k + 1);
  }

  if (gp == 0) sysst(hlast + (size_t)mb_*512 + mhc, hl_reg);
  __syncthreads();
  if (tid == 0){
    fbump(&g_FD[wg*16], B + 40);
    fbump(&g_FB[wg*16], B + 40);
  }

  // ---------------- fc on block 0 ----------------
  if (wg == 0){
    if (tid < NWG) waitflag(&g_FD[(unsigned)tid*16], B + 40);
    __syncthreads();
    for (int o = wave; o < 384; o += 8){
      int bbq = o / 3, cls = o - bbq*3;
      const float* hr = hlast + (size_t)bbq*512 + lane*8;
      const float* wr = p.fcW + (size_t)cls*512 + lane*8;
      float2 ha = sysld2(hr), hb = sysld2(hr+2), hc2 = sysld2(hr+4), hd = sysld2(hr+6);
      float4 w0 = *(const float4*)wr, w1 = *(const float4*)(wr + 4);
      float v = ha.x*w0.x + ha.y*w0.y + hb.x*w0.z + hb.y*w0.w
              + hc2.x*w1.x + hc2.y*w1.y + hd.x*w1.z + hd.y*w1.w;
      v = wsum(v);
      if (lane == 0) p.out[o] = v + p.fcb[cls];
    }
  }
}

extern "C" void kernel_launch(void* const* d_in, const int* in_sizes, int n_in,
                              void* d_out, int out_size, void* d_ws, size_t ws_size,
                              hipStream_t stream) {
  if (ws_size < WS_FLOATS * sizeof(float)) return;  // fail clean, not OOB
  Params prm;
  prm.premise = (const int*)d_in[0];
  prm.plen    = (const int*)d_in[1];
  prm.hyp     = (const int*)d_in[2];
  prm.hlen    = (const int*)d_in[3];
  prm.embed   = (const float*)d_in[4];
  prm.pWih    = (const float*)d_in[5];
  prm.pWhh    = (const float*)d_in[6];
  prm.pb      = (const float*)d_in[7];
  prm.hWih    = (const float*)d_in[8];
  prm.hWhh    = (const float*)d_in[9];
  prm.hb      = (const float*)d_in[10];
  prm.mWih    = (const float*)d_in[11];
  prm.mWhh    = (const float*)d_in[12];
  prm.mb      = (const float*)d_in[13];
  prm.we      = (const float*)d_in[14];
  prm.Ws      = (const float*)d_in[15];
  prm.Wt      = (const float*)d_in[16];
  prm.Wm      = (const float*)d_in[17];
  prm.fcW     = (const float*)d_in[18];
  prm.fcb     = (const float*)d_in[19];
  prm.out     = (float*)d_out;
  prm.ws      = (float*)d_ws;

  k_s0   <<<dim3(1024), dim3(TPB), 0, stream>>>(prm);
  k_s1   <<<dim3(768),  dim3(TPB), 0, stream>>>(prm);
  k_enc  <<<dim3(NWG),  dim3(TPB), 0, stream>>>(prm);
  k_s4   <<<dim3(448),  dim3(TPB), 0, stream>>>(prm);
  k_match<<<dim3(NWG),  dim3(TPB), 0, stream>>>(prm);
}

// Round 7
// 5390.382 us; speedup vs baseline: 1.8864x; 1.8864x over previous
//
#include <hip/hip_runtime.h>

// MatchLSTM, fp32, round 7.
// Key change vs R5/R6: ALL hot-loop weight streams are k-major and read
// lane-coalesced (one 256-512B segment per wave-load) instead of per-thread
// row gathers (32 lines/instr -> TA-bound, the measured R5/R6 wall).
// Encoder: 128 blocks per sequence (8 bg x 16 jg), thread owns 4 gates of one
// hc. Match: 256 blocks (8 bg x 32 jg), k-half split threads, 2-hop flags.

#define NWG 256
#define TPB 512

typedef float f8v __attribute__((ext_vector_type(8)));

// ---- workspace layout (float offsets) ----
#define O_XPP      0ull          // [64][128][2048] premise input proj (+bias)
#define O_HTMW     0ull          // overlay after encoders: [32][128][2048]
#define O_HTWT     8388608ull    // [32][128][512]
#define O_WSHS     10485760ull   // [64][128][512]
#define O_XPH      16777216ull   // [32][128][2048]
#define O_HST      25165824ull   // [64][512][128]  masked premise h (k-major)
#define O_HS2      29360128ull   // [64][128][512]  masked premise h (h-major)
#define O_HTT      33554432ull   // [32][512][128]  masked hyp h (k-major)
#define O_WIHTP    35651584ull   // [300][2048] perm
#define O_WIHTH    36265984ull
#define O_WHHPP    36880384ull   // [512 k][2048 jp] premise Whh (k-major!)
#define O_WHHPH    37928960ull   // [512 k][2048 jp] hyp Whh
#define O_DW       38977536ull   // [1024 k][2048 jp] match (mWihL rows 0-511 | mWhh rows 512-1023)
#define O_WST      41074688ull   // [512][512] k-major
#define O_WTT      41336832ull
#define O_MWIHRT   41598976ull   // [512][2048] perm
#define O_BPP      42647552ull   // [2048] perm biases
#define O_BPH      42649600ull
#define O_BPM      42651648ull
#define O_HT2      42653696ull   // [2][128][512] premise h double buffer (coherent)
#define O_HMT2     42784768ull   // [2][128][512] hyp-enc h dbuf, then match h dbuf
#define O_AK2      42981376ull   // [128][512] (coherent)
#define O_HLAST    43046912ull   // [128][512] (coherent)
#define O_WMT      43112448ull   // [512 k][512 c] Wm transposed
#define WS_FLOATS  43374592ull

__device__ unsigned g_FE[NWG * 16];      // encoder step flags (64B padded)
__device__ unsigned g_FB[NWG * 16];      // match BC flags
__device__ unsigned g_FD[NWG * 16];      // match D flags

struct Params {
  const int* premise; const int* plen; const int* hyp; const int* hlen;
  const float* embed;
  const float* pWih; const float* pWhh; const float* pb;
  const float* hWih; const float* hWhh; const float* hb;
  const float* mWih; const float* mWhh; const float* mb;
  const float* we; const float* Ws; const float* Wt; const float* Wm;
  const float* fcW; const float* fcb;
  float* out; float* ws;
};

// ---- coherent (system-scope, L2-bypassing) accessors for mutable state ----
__device__ __forceinline__ float2 sysld2(const float* p){
  unsigned long long u = __hip_atomic_load((const unsigned long long*)p,
      __ATOMIC_RELAXED, __HIP_MEMORY_SCOPE_SYSTEM);
  union { unsigned long long u; float2 f; } c; c.u = u; return c.f;
}
__device__ __forceinline__ void sysst(float* p, float v){
  union { float f; unsigned u; } c; c.f = v;
  __hip_atomic_store((unsigned*)p, c.u, __ATOMIC_RELAXED, __HIP_MEMORY_SCOPE_SYSTEM);
}
__device__ __forceinline__ void fbump(unsigned* a, unsigned v){
  __hip_atomic_store(a, v, __ATOMIC_RELAXED, __HIP_MEMORY_SCOPE_SYSTEM);
}
__device__ __forceinline__ unsigned fread_(const unsigned* a){
  return __hip_atomic_load(a, __ATOMIC_RELAXED, __HIP_MEMORY_SCOPE_SYSTEM);
}
__device__ __forceinline__ void waitflag(const unsigned* a, unsigned tgt){
  while ((int)(fread_(a) - tgt) < 0) __builtin_amdgcn_s_sleep(2);
}

__device__ __forceinline__ float sigf(float x){ return 1.0f/(1.0f + __expf(-x)); }
__device__ __forceinline__ float tanhf_(float x){ return 2.0f/(1.0f + __expf(-2.0f*x)) - 1.0f; }

__device__ __forceinline__ float wsum(float v){
  #pragma unroll
  for (int o = 32; o > 0; o >>= 1) v += __shfl_xor(v, o, 64);
  return v;
}
__device__ __forceinline__ float wmaxr(float v){
  #pragma unroll
  for (int o = 32; o > 0; o >>= 1) v = fmaxf(v, __shfl_xor(v, o, 64));
  return v;
}

// ================= S0: weight layout transforms (grid 1024) =================
__global__ __launch_bounds__(TPB) void k_s0(Params p){
  const int tid0 = blockIdx.x * TPB + threadIdx.x;
  const int stride = gridDim.x * TPB;
  float* const ws = p.ws;
  float* const WihTp  = ws + O_WIHTP;
  float* const WihTh  = ws + O_WIHTH;
  float* const WhhPP  = ws + O_WHHPP;
  float* const WhhPH  = ws + O_WHHPH;
  float* const DW     = ws + O_DW;
  float* const WsT    = ws + O_WST;
  float* const WtT    = ws + O_WTT;
  float* const WmT    = ws + O_WMT;
  float* const mWihRT = ws + O_MWIHRT;
  float* const bpP    = ws + O_BPP;
  float* const bpH    = ws + O_BPH;
  float* const bpM    = ws + O_BPM;

  for (int idx = tid0; idx < 300*2048; idx += stride){
    int e = idx >> 11, jp = idx & 2047;
    int oc = (jp & 3) * 512 + (jp >> 2);
    WihTp[idx] = p.pWih[(size_t)oc*300 + e];
    WihTh[idx] = p.hWih[(size_t)oc*300 + e];
  }
  // encoder recurrent weights, k-major [k][jp], jp = hc*4+gate
  for (int idx = tid0; idx < 512*2048; idx += stride){
    int jp = idx & 2047, k = idx >> 11;
    int oc = (jp & 3) * 512 + (jp >> 2);
    WhhPP[idx] = p.pWhh[(size_t)oc*512 + k];
    WhhPH[idx] = p.hWhh[(size_t)oc*512 + k];
  }
  // match weights, k-major [1024][2048]: rows 0-511 = mWih left, 512-1023 = mWhh
  for (int idx = tid0; idx < 1024*2048; idx += stride){
    int jp = idx & 2047, k = idx >> 11;
    int oc = (jp & 3) * 512 + (jp >> 2);
    DW[idx] = (k < 512) ? p.mWih[(size_t)oc*1024 + k]
                        : p.mWhh[(size_t)oc*512 + (k - 512)];
  }
  for (int idx = tid0; idx < 512*512; idx += stride){
    int k = idx >> 9, h = idx & 511;
    WsT[idx] = p.Ws[(size_t)h*512 + k];
    WtT[idx] = p.Wt[(size_t)h*512 + k];
    WmT[idx] = p.Wm[(size_t)h*512 + k];
  }
  for (int idx = tid0; idx < 512*2048; idx += stride){
    int k = idx >> 11, jp = idx & 2047;
    int oc = (jp & 3) * 512 + (jp >> 2);
    mWihRT[idx] = p.mWih[(size_t)oc*1024 + 512 + k];
  }
  for (int idx = tid0; idx < 2048; idx += stride){
    int oc = (idx & 3) * 512 + (idx >> 2);
    bpP[idx] = p.pb[oc]; bpH[idx] = p.hb[oc]; bpM[idx] = p.mb[oc];
  }
}

// ================= S1: XP = embed[tokens] @ WihT + bias (grid 768) ==========
__global__ __launch_bounds__(TPB) void k_s1(Params p){
  const int tid = threadIdx.x, lane = tid & 63, wave = tid >> 6;
  const int gwave = blockIdx.x * 8 + wave;
  const int wstride = gridDim.x * 8;
  float* const ws = p.ws;
  float* const XPp   = ws + O_XPP;
  float* const XPh   = ws + O_XPH;
  const float* WihTp = ws + O_WIHTP;
  const float* WihTh = ws + O_WIHTH;
  const float* bpP   = ws + O_BPP;
  const float* bpH   = ws + O_BPH;

  for (int task = gwave; task < 6144; task += wstride){
    const bool prem = task < 4096;
    int rb, cb;
    if (prem){ cb = task >> 10; rb = task & 1023; }
    else { int t2 = task - 4096; cb = t2 >> 9; rb = t2 & 511; }
    const int r0 = rb * 8;
    const int* toks = prem ? p.premise : p.hyp;
    const float* wT = prem ? WihTp : WihTh;
    const float* bias = prem ? bpP : bpH;
    float* outp = prem ? XPp : XPh;
    const int j0 = cb * 512 + lane * 8;
    const float* xr[8];
    #pragma unroll
    for (int r = 0; r < 8; ++r) xr[r] = p.embed + (size_t)toks[r0 + r] * 300;
    f8v bias8 = *(const f8v*)(bias + j0);
    float acc[8][8];
    #pragma unroll
    for (int r = 0; r < 8; ++r){
      #pragma unroll
      for (int i = 0; i < 8; ++i) acc[r][i] = 0.f;
    }
    for (int e = 0; e < 300; ++e){
      f8v w8 = *(const f8v*)(wT + (size_t)e * 2048 + j0);
      #pragma unroll
      for (int r = 0; r < 8; ++r){
        float xv = xr[r][e];
        #pragma unroll
        for (int i = 0; i < 8; ++i) acc[r][i] += xv * w8[i];
      }
    }
    #pragma unroll
    for (int r = 0; r < 8; ++r){
      f8v o8;
      #pragma unroll
      for (int i = 0; i < 8; ++i) o8[i] = acc[r][i] + bias8[i];
      *(f8v*)(outp + (size_t)(r0 + r) * 2048 + j0) = o8;
    }
  }
}

// ====== fused encoders: blocks 0-127 premise, 128-255 hypothesis ============
// Block (bg: 16 rows, jg: 32 hc). Thread (b16 = tid>>5, j32 = tid&31) owns all
// 4 gates of hc = jg*32+j32 for row b16. Weight reads coalesced (512B/instr).
__global__ __launch_bounds__(TPB, 2) void k_enc(Params p){
  const int wg = blockIdx.x, tid = threadIdx.x;
  const bool prem = wg < 128;
  const int lw = prem ? wg : wg - 128;
  const int jg = lw & 15, bg = lw >> 4;
  const int T = prem ? 64 : 32;
  const float* XP = p.ws + (prem ? O_XPP : O_XPH);
  const float* W  = p.ws + (prem ? O_WHHPP : O_WHHPH);   // [512][2048]
  const int* lens = prem ? p.plen : p.hlen;
  float* hbuf  = p.ws + (prem ? O_HT2 : O_HMT2);
  float* houtT = p.ws + (prem ? O_HST : O_HTT);
  float* hout2 = prem ? (p.ws + O_HS2) : nullptr;
  __shared__ float hst[16*520];
  __shared__ unsigned shB;
  if (tid == 0) shB = fread_(&g_FE[wg*16]);
  __syncthreads();
  const unsigned B = shB;
  const int b16 = tid >> 5, j32 = tid & 31;
  const int b = bg*16 + b16, hc = jg*32 + j32;
  const int mylen = lens[b];
  const int fb0 = (prem ? 0 : 128) + bg*16;
  float c_reg = 0.f;

  for (int t = 0; t < T; ++t){
    const float* hin = hbuf + (size_t)(t & 1)*65536;
    float*      hout = hbuf + (size_t)((t+1) & 1)*65536;
    if (t > 0){
      if (tid < 16) waitflag(&g_FE[(unsigned)(fb0 + tid)*16], B + t);
      __syncthreads();
      const float* srcb = hin + (size_t)bg*16*512;
      for (int off = tid*2; off < 8192; off += 1024){   // lane-coalesced stage
        int r = off >> 9, c = off & 511;
        *(float2*)(hst + r*520 + c) = sysld2(srcb + r*512 + c);
      }
      __syncthreads();
    }
    float4 xg = *(const float4*)(XP + ((size_t)t*128 + b)*2048 + hc*4);
    float a0 = xg.x, a1 = xg.y, a2 = xg.z, a3 = xg.w;
    if (t > 0){
      const float* hr = hst + b16*520;
      const float* wk = W + (size_t)hc*4;
      #pragma unroll 2
      for (int k = 0; k < 512; k += 4){
        float4 h4 = *(const float4*)(hr + k);
        float4 w0 = *(const float4*)(wk + (size_t)(k+0)*2048);
        float4 w1 = *(const float4*)(wk + (size_t)(k+1)*2048);
        float4 w2 = *(const float4*)(wk + (size_t)(k+2)*2048);
        float4 w3 = *(const float4*)(wk + (size_t)(k+3)*2048);
        a0 += h4.x*w0.x + h4.y*w1.x + h4.z*w2.x + h4.w*w3.x;
        a1 += h4.x*w0.y + h4.y*w1.y + h4.z*w2.y + h4.w*w3.y;
        a2 += h4.x*w0.z + h4.y*w1.z + h4.z*w2.z + h4.w*w3.z;
        a3 += h4.x*w0.w + h4.y*w1.w + h4.z*w2.w + h4.w*w3.w;
      }
    }
    float iv = sigf(a0), fv = sigf(a1), gv = tanhf_(a2), ov = sigf(a3);
    c_reg = fv * c_reg + iv * gv;
    float hv = ov * tanhf_(c_reg);
    sysst(hout + (size_t)b*512 + hc, hv);       // coherent recurrence state
    float hm = (t < mylen) ? hv : 0.f;          // masked outputs (normal stores)
    houtT[((size_t)t*512 + hc)*128 + b] = hm;
    if (hout2) hout2[((size_t)t*128 + b)*512 + hc] = hm;
    __syncthreads();                             // drains vmem before flag
    if (tid == 0) fbump(&g_FE[wg*16], B + t + 1);
  }
}

// ================= S4: Ws_hs, htWt, htmW (grid 448) =========================
__global__ __launch_bounds__(TPB) void k_s4(Params p){
  const int tid = threadIdx.x, lane = tid & 63, wave = tid >> 6;
  const int gwave = blockIdx.x * 8 + wave;
  const int wstride = gridDim.x * 8;
  float* const ws = p.ws;
  const float* h_sT   = ws + O_HST;
  const float* h_tT   = ws + O_HTT;
  const float* WsT    = ws + O_WST;
  const float* WtT    = ws + O_WTT;
  const float* mWihRT = ws + O_MWIHRT;
  const float* bpM    = ws + O_BPM;
  float* const Ws_hs  = ws + O_WSHS;
  float* const htWt   = ws + O_HTWT;
  float* const htmW   = ws + O_HTMW;

  for (int task = gwave; task < 3584; task += wstride){
    const float* src; const float* wT; const float* bias; float* outp;
    int rb, cb, cols;
    if (task < 1024){ rb = task;        cb = 0;            src = h_sT; wT = WsT;    bias = nullptr; outp = Ws_hs; cols = 512; }
    else if (task < 1536){ rb = task-1024; cb = 0;         src = h_tT; wT = WtT;    bias = nullptr; outp = htWt;  cols = 512; }
    else { int t2 = task - 1536; cb = t2 >> 9; rb = t2 & 511; src = h_tT; wT = mWihRT; bias = bpM;  outp = htmW;  cols = 2048; }
    const int r0 = rb * 8;
    const int j0 = cb * 512 + lane * 8;
    const float* xr[8];
    #pragma unroll
    for (int r = 0; r < 8; ++r){
      int row = r0 + r;
      xr[r] = src + (size_t)(row >> 7) * 65536 + (row & 127);  // [t][k][b]
    }
    f8v bias8 = {0,0,0,0,0,0,0,0};
    if (bias) bias8 = *(const f8v*)(bias + j0);
    float acc[8][8];
    #pragma unroll
    for (int r = 0; r < 8; ++r){
      #pragma unroll
      for (int i = 0; i < 8; ++i) acc[r][i] = 0.f;
    }
    for (int k = 0; k < 512; ++k){
      f8v w8 = *(const f8v*)(wT + (size_t)k * cols + j0);
      #pragma unroll
      for (int r = 0; r < 8; ++r){
        float xv = xr[r][(size_t)k * 128];
        #pragma unroll
        for (int i = 0; i < 8; ++i) acc[r][i] += xv * w8[i];
      }
    }
    #pragma unroll
    for (int r = 0; r < 8; ++r){
      f8v o8;
      #pragma unroll
      for (int i = 0; i < 8; ++i) o8[i] = acc[r][i] + bias8[i];
      *(f8v*)(outp + (size_t)(r0 + r) * (size_t)cols + j0) = o8;
    }
  }
}

// ================= match-LSTM loop + fc (persistent, grid 256) ==============
// bg = wg>>5 (16 rows each), jg = wg&31 (16 hc each). Blocks jg<16 also run BC
// for row bb = bg*16+jg. D threads: (kh = tid>>8, b16 = (tid>>4)&15, jt=tid&15)
// -> hc = jg*16+jt, k-half kh; partial join via LDS; cell update on kh==0.
__global__ __launch_bounds__(TPB, 2) void k_match(Params p){
  const int wg = blockIdx.x, tid = threadIdx.x;
  const int lane = tid & 63, wave = tid >> 6;
  const int bg = wg >> 5, jg = wg & 31;
  const bool bcrole = jg < 16;
  const int bb = bg*16 + jg;
  __shared__ float Sa[16*520];
  __shared__ float Sh[16*520];
  __shared__ float xch[1024];
  __shared__ float bcb[1152];   // hm[512] | q[512] | sc[64] | al[64]
  __shared__ unsigned shB;
  if (tid == 0) shB = fread_(&g_FD[wg*16]);
  __syncthreads();
  const unsigned B = shB;

  float* const ws = p.ws;
  const float* htmW  = ws + O_HTMW;
  const float* htWt  = ws + O_HTWT;
  const float* Ws_hs = ws + O_WSHS;
  const float* h_s2  = ws + O_HS2;
  const float* DW    = ws + O_DW;
  const float* WmT   = ws + O_WMT;
  float* const hmT2  = ws + O_HMT2;
  float* const ak2   = ws + O_AK2;
  float* const hlast = ws + O_HLAST;

  const int kh = tid >> 8, b16 = (tid >> 4) & 15, jt = tid & 15;
  const int hcD = jg*16 + jt;
  const int rowD = bg*16 + b16;
  const int hyplen_b = p.hlen[rowD];
  float c_reg = 0.f, hl_reg = 0.f;

  for (int k = 0; k < 32; ++k){
    const float* hmin  = hmT2 + (size_t)(k & 1)*65536;
    float*       hmout = hmT2 + (size_t)((k + 1) & 1)*65536;

    // ---- BC (blocks jg<16): q + scores + softmax + a_k for row bb ----
    if (bcrole){
      if (k > 0){
        if (tid < 32) waitflag(&g_FD[(unsigned)(bg*32 + tid)*16], B + k);
        __syncthreads();
        if (tid < 256) *(float2*)(bcb + tid*2) = sysld2(hmin + (size_t)bb*512 + tid*2);
        __syncthreads();
      }
      float qv = htWt[((size_t)k*128 + bb)*512 + tid];
      if (k > 0){
        float q0=0.f,q1=0.f,q2=0.f,q3=0.f;
        for (int kk = 0; kk < 512; kk += 4){
          q0 += bcb[kk]   * WmT[(size_t)(kk)  *512 + tid];
          q1 += bcb[kk+1] * WmT[(size_t)(kk+1)*512 + tid];
          q2 += bcb[kk+2] * WmT[(size_t)(kk+2)*512 + tid];
          q3 += bcb[kk+3] * WmT[(size_t)(kk+3)*512 + tid];
        }
        qv += (q0 + q1) + (q2 + q3);
      }
      __syncthreads();
      bcb[512 + tid] = qv;
      __syncthreads();
      float q8[8];
      #pragma unroll
      for (int j = 0; j < 8; ++j) q8[j] = bcb[512 + lane*8 + j];
      float4 e0 = *(const float4*)(p.we + lane*8);
      float4 e1 = *(const float4*)(p.we + lane*8 + 4);
      #pragma unroll
      for (int si = 0; si < 8; ++si){
        int s = wave*8 + si;
        const float* wsr = Ws_hs + ((size_t)s*128 + bb)*512 + lane*8;
        float4 s0 = *(const float4*)wsr;
        float4 s1 = *(const float4*)(wsr + 4);
        float v = tanhf_(s0.x + q8[0])*e0.x + tanhf_(s0.y + q8[1])*e0.y
                + tanhf_(s0.z + q8[2])*e0.z + tanhf_(s0.w + q8[3])*e0.w
                + tanhf_(s1.x + q8[4])*e1.x + tanhf_(s1.y + q8[5])*e1.y
                + tanhf_(s1.z + q8[6])*e1.z + tanhf_(s1.w + q8[7])*e1.w;
        v = wsum(v);
        if (lane == 0) bcb[1024 + s] = v;
      }
      __syncthreads();
      if (wave == 0){
        float v = bcb[1024 + lane];
        float m = wmaxr(v);
        float ex = __expf(v - m);
        float sm = wsum(ex);
        bcb[1088 + lane] = ex / sm;
      }
      __syncthreads();
      {
        float acc = 0.f;
        const float* hsb = h_s2 + (size_t)bb*512 + tid;
        #pragma unroll 4
        for (int s = 0; s < 64; s += 4){
          float4 al = *(const float4*)(bcb + 1088 + s);
          acc += al.x * hsb[(size_t)(s+0)*65536]
               + al.y * hsb[(size_t)(s+1)*65536]
               + al.z * hsb[(size_t)(s+2)*65536]
               + al.w * hsb[(size_t)(s+3)*65536];
        }
        sysst(ak2 + (size_t)bb*512 + tid, acc);
      }
      __syncthreads();
      if (tid == 0) fbump(&g_FB[wg*16], B + k + 1);
    } else {
      if (k > 0 && tid < 32) waitflag(&g_FD[(unsigned)(bg*32 + tid)*16], B + k);
    }
    // all blocks: wait a_k(k) ready from this bg's 16 BC blocks
    if (tid >= 32 && tid < 48) waitflag(&g_FB[(unsigned)(bg*32 + (tid - 32))*16], B + k + 1);
    __syncthreads();
    // ---- stage a_k and h_m rows [bg*16..+16), lane-coalesced ----
    {
      const float* sa = ak2 + (size_t)bg*16*512;
      for (int off = tid*2; off < 8192; off += 1024){
        int r = off >> 9, c = off & 511;
        *(float2*)(Sa + r*520 + c) = sysld2(sa + r*512 + c);
      }
      if (k > 0){
        const float* shh = hmin + (size_t)bg*16*512;
        for (int off = tid*2; off < 8192; off += 1024){
          int r = off >> 9, c = off & 511;
          *(float2*)(Sh + r*520 + c) = sysld2(shh + r*512 + c);
        }
      } else {
        for (int off = tid*2; off < 8192; off += 1024){
          int r = off >> 9, c = off & 511;
          Sh[r*520 + c] = 0.f; Sh[r*520 + c + 1] = 0.f;
        }
      }
    }
    __syncthreads();
    // ---- D compute: coalesced k-major DW stream ----
    {
      const float* S = (kh ? Sh : Sa) + b16*520;
      const float* wk = DW + (size_t)(kh*512)*2048 + (size_t)hcD*4;
      float a0=0.f,a1=0.f,a2=0.f,a3=0.f;
      #pragma unroll 2
      for (int kk = 0; kk < 512; kk += 4){
        float4 h4 = *(const float4*)(S + kk);
        float4 w0 = *(const float4*)(wk + (size_t)(kk+0)*2048);
        float4 w1 = *(const float4*)(wk + (size_t)(kk+1)*2048);
        float4 w2 = *(const float4*)(wk + (size_t)(kk+2)*2048);
        float4 w3 = *(const float4*)(wk + (size_t)(kk+3)*2048);
        a0 += h4.x*w0.x + h4.y*w1.x + h4.z*w2.x + h4.w*w3.x;
        a1 += h4.x*w0.y + h4.y*w1.y + h4.z*w2.y + h4.w*w3.y;
        a2 += h4.x*w0.z + h4.y*w1.z + h4.z*w2.z + h4.w*w3.z;
        a3 += h4.x*w0.w + h4.y*w1.w + h4.z*w2.w + h4.w*w3.w;
      }
      if (kh == 1){ float4 o = {a0,a1,a2,a3}; *(float4*)(xch + (b16*16 + jt)*4) = o; }
      __syncthreads();
      if (kh == 0){
        float4 xo = *(const float4*)(xch + (b16*16 + jt)*4);
        float4 xg = *(const float4*)(htmW + ((size_t)k*128 + rowD)*2048 + hcD*4);
        a0 += xo.x + xg.x; a1 += xo.y + xg.y; a2 += xo.z + xg.z; a3 += xo.w + xg.w;
        float iv = sigf(a0), fv = sigf(a1), gv = tanhf_(a2), ov = sigf(a3);
        c_reg = fv * c_reg + iv * gv;
        float hv = ov * tanhf_(c_reg);
        sysst(hmout + (size_t)rowD*512 + hcD, hv);
        if (k + 1 == hyplen_b) hl_reg = hv;
      }
    }
    __syncthreads();
    if (tid == 0) fbump(&g_FD[wg*16], B + k + 1);
  }

  if (kh == 0) sysst(hlast + (size_t)rowD*512 + hcD, hl_reg);
  __syncthreads();
  if (tid == 0){ fbump(&g_FD[wg*16], B + 40); fbump(&g_FB[wg*16], B + 40); }

  // ---------------- fc on block 0 ----------------
  if (wg == 0){
    if (tid < NWG) waitflag(&g_FD[(unsigned)tid*16], B + 40);
    __syncthreads();
    for (int o = wave; o < 384; o += 8){
      int bbq = o / 3, cls = o - bbq*3;
      const float* hr = hlast + (size_t)bbq*512 + lane*8;
      const float* wr = p.fcW + (size_t)cls*512 + lane*8;
      float2 ha = sysld2(hr), hb = sysld2(hr+2), hc2 = sysld2(hr+4), hd = sysld2(hr+6);
      float4 w0 = *(const float4*)wr, w1 = *(const float4*)(wr + 4);
      float v = ha.x*w0.x + ha.y*w0.y + hb.x*w0.z + hb.y*w0.w
              + hc2.x*w1.x + hc2.y*w1.y + hd.x*w1.z + hd.y*w1.w;
      v = wsum(v);
      if (lane == 0) p.out[o] = v + p.fcb[cls];
    }
  }
}

extern "C" void kernel_launch(void* const* d_in, const int* in_sizes, int n_in,
                              void* d_out, int out_size, void* d_ws, size_t ws_size,
                              hipStream_t stream) {
  if (ws_size < WS_FLOATS * sizeof(float)) return;  // fail clean, not OOB
  Params prm;
  prm.premise = (const int*)d_in[0];
  prm.plen    = (const int*)d_in[1];
  prm.hyp     = (const int*)d_in[2];
  prm.hlen    = (const int*)d_in[3];
  prm.embed   = (const float*)d_in[4];
  prm.pWih    = (const float*)d_in[5];
  prm.pWhh    = (const float*)d_in[6];
  prm.pb      = (const float*)d_in[7];
  prm.hWih    = (const float*)d_in[8];
  prm.hWhh    = (const float*)d_in[9];
  prm.hb      = (const float*)d_in[10];
  prm.mWih    = (const float*)d_in[11];
  prm.mWhh    = (const float*)d_in[12];
  prm.mb      = (const float*)d_in[13];
  prm.we      = (const float*)d_in[14];
  prm.Ws      = (const float*)d_in[15];
  prm.Wt      = (const float*)d_in[16];
  prm.Wm      = (const float*)d_in[17];
  prm.fcW     = (const float*)d_in[18];
  prm.fcb     = (const float*)d_in[19];
  prm.out     = (float*)d_out;
  prm.ws      = (float*)d_ws;

  k_s0   <<<dim3(1024), dim3(TPB), 0, stream>>>(prm);
  k_s1   <<<dim3(768),  dim3(TPB), 0, stream>>>(prm);
  k_enc  <<<dim3(NWG),  dim3(TPB), 0, stream>>>(prm);
  k_s4   <<<dim3(448),  dim3(TPB), 0, stream>>>(prm);
  k_match<<<dim3(NWG),  dim3(TPB), 0, stream>>>(prm);
}